// Round 11
// baseline (153.198 us; speedup 1.0000x reference)
//
#include <hip/hip_runtime.h>
#include <hip/hip_cooperative_groups.h>

namespace cg = cooperative_groups;

#define NUM_BINS  512
#define NUM_NODES 128
#define K_ELEMS   16384
#define N_PAIRS   1024
#define NCOPY     32
#define NBLK      256
#define NTHR      1024
#define ROWS_PB   4

typedef float f32x4 __attribute__((ext_vector_type(4)));
typedef unsigned int   u32;
typedef unsigned short u16;

__device__ __forceinline__ void gfadd(float* p, float v) { unsafeAtomicAdd(p, v); }

// ============================ fused cooperative ============================
// 256 blocks x 1024 thr, 4 rows/block, 1 block/CU (VGPR<=128 enforced by the
// 1024-thr launchability constraint; LDS 66KB <= 160KB). Codes for 4 rows
// stay in 32 u32 registers across a grid sync -- no codes round-trip.
// ---------------------------------------------------------------------------

__device__ __forceinline__ void zero_lds(u32* lh, int t)
{
    uint4* lh4 = (uint4*)lh;
    #pragma unroll
    for (int k = 0; k < NUM_BINS * NCOPY / 4 / NTHR; ++k) {
        uint4 z; z.x = z.y = z.z = z.w = 0u;
        lh4[t + k * NTHR] = z;
    }
}

// LDS histogram of one row (fixed-point u32 ds_add_u32 = fast bank-parallel
// path; 32 copies, copy=t&31 -> bank=copy, 2 lanes/bank conflict-free).
// Also packs lookup codes (floor(r*512+0.5) | 0xFFFF-invalid) into pc[8].
__device__ __forceinline__ float hist_row(
    const float* __restrict__ residuals, const float* __restrict__ weights,
    int row, int t, int copy, u32* lh, u32 (&pc)[8])
{
    const f32x4* r4 = (const f32x4*)(residuals + (size_t)row * K_ELEMS);
    const f32x4* w4 = (const f32x4*)(weights   + (size_t)row * K_ELEMS);
    float wsum = 0.0f;
    #pragma unroll
    for (int it = 0; it < K_ELEMS / 4 / NTHR; ++it) {      // 4 iters
        f32x4 r = __builtin_nontemporal_load(r4 + (t + it * NTHR));
        f32x4 w = __builtin_nontemporal_load(w4 + (t + it * NTHR));
        wsum += w[0] + w[1] + w[2] + w[3];                 // UNMASKED sum
        u32 p0 = 0, p1 = 0;
        #pragma unroll
        for (int c = 0; c < 4; ++c) {
            int b = (int)floorf(r[c] * 512.0f);
            if ((unsigned)b < 512u)
                atomicAdd(&lh[b * NCOPY + copy], (u32)fmaf(w[c], 65536.0f, 0.5f));
            int lb = (int)floorf(r[c] * 512.0f + 0.5f);
            u32 code = (((unsigned)lb < 512u) & (w[c] > 0.0f)) ? (u32)lb : 0xFFFFu;
            if (c == 0) p0 |= code;
            if (c == 1) p0 |= code << 16;
            if (c == 2) p1 |= code;
            if (c == 3) p1 |= code << 16;
        }
        pc[it * 2] = p0; pc[it * 2 + 1] = p1;
    }
    return wsum;
}

// flush LDS histogram to hist[s],hist[d]: thread pair (2b,2b+1) owns bin b,
// each half sums 16 rotated copies (2 lanes/bank), shfl-combines, even half
// -> src row, odd half -> dst row. Coalesced global f32 atomics (R6-proven).
__device__ __forceinline__ void flush_row(const u32* lh, float* __restrict__ hist,
                                          int s, int d, int t)
{
    const int bin  = t >> 1;
    const int half = t & 1;
    u32 tot = 0;
    #pragma unroll
    for (int cc = 0; cc < 16; ++cc)
        tot += lh[bin * NCOPY + (((bin + cc) & 15) | (half << 4))];
    tot += (u32)__shfl_xor((int)tot, 1);
    float v = (float)tot * (1.0f / 65536.0f);
    if (half == 0) gfadd(&hist[s * NUM_BINS + bin], v);
    else           gfadd(&hist[d * NUM_BINS + bin], v);
}

// lookup one row from register codes; cdf rows staged at fl[0..511] (src) and
// fl[512..1023] (dst); non-temporal output stores.
__device__ __forceinline__ void lookup_row(
    const u32 (&pc)[8], const float* fl, int row, int t,
    float* __restrict__ out_src, float* __restrict__ out_dst)
{
    f32x4* os = (f32x4*)(out_src + (size_t)row * K_ELEMS);
    f32x4* od = (f32x4*)(out_dst + (size_t)row * K_ELEMS);
    #pragma unroll
    for (int it = 0; it < K_ELEMS / 4 / NTHR; ++it) {
        u32 p0 = pc[it * 2], p1 = pc[it * 2 + 1];
        u32 c0 = p0 & 0xFFFFu, c1 = p0 >> 16, c2 = p1 & 0xFFFFu, c3 = p1 >> 16;
        f32x4 osv, odv;
        osv[0] = (c0 != 0xFFFFu) ? fl[c0] : 2.0f;
        odv[0] = (c0 != 0xFFFFu) ? fl[512 + c0] : 2.0f;
        osv[1] = (c1 != 0xFFFFu) ? fl[c1] : 2.0f;
        odv[1] = (c1 != 0xFFFFu) ? fl[512 + c1] : 2.0f;
        osv[2] = (c2 != 0xFFFFu) ? fl[c2] : 2.0f;
        odv[2] = (c2 != 0xFFFFu) ? fl[512 + c2] : 2.0f;
        osv[3] = (c3 != 0xFFFFu) ? fl[c3] : 2.0f;
        odv[3] = (c3 != 0xFFFFu) ? fl[512 + c3] : 2.0f;
        __builtin_nontemporal_store(osv, os + (t + it * NTHR));
        __builtin_nontemporal_store(odv, od + (t + it * NTHR));
    }
}

__global__ __launch_bounds__(NTHR, 4) void fused_kernel(
    const float* __restrict__ residuals, const float* __restrict__ weights,
    const int* __restrict__ src, const int* __restrict__ dst,
    float* __restrict__ hist, float* __restrict__ tw,
    float* __restrict__ out_src, float* __restrict__ out_dst)
{
    cg::grid_group grid = cg::this_grid();
    __shared__ u32 lh[NUM_BINS * NCOPY];   // 65536 B
    __shared__ float swsum[16];
    __shared__ float rowtot[ROWS_PB];

    const int blk  = blockIdx.x;           // 0..255
    const int t    = threadIdx.x;          // 0..1023
    const int copy = t & 31;
    const int row0 = blk * ROWS_PB;

    int s0 = src[row0],     d0 = dst[row0];
    int s1 = src[row0 + 1], d1 = dst[row0 + 1];
    int s2 = src[row0 + 2], d2 = dst[row0 + 2];
    int s3 = src[row0 + 3], d3 = dst[row0 + 3];

    u32 pc0[8], pc1[8], pc2[8], pc3[8];

    // distributed zero of hist+tw (contiguous 65664 floats; 256*1024 covers)
    {
        int i = blk * NTHR + t;
        if (i < NUM_NODES * NUM_BINS + NUM_NODES) hist[i] = 0.0f;
    }

    // ---- row 0 histogram (before grid.sync; flush must wait for zero) ----
    zero_lds(lh, t);
    __syncthreads();
    float ws0 = hist_row(residuals, weights, row0, t, copy, lh, pc0);
    #pragma unroll
    for (int off = 32; off > 0; off >>= 1) ws0 += __shfl_down(ws0, off, 64);
    if ((t & 63) == 0) swsum[t >> 6] = ws0;
    __syncthreads();
    if (t == 0) {
        float a = 0.0f;
        for (int i = 0; i < 16; ++i) a += swsum[i];
        rowtot[0] = a;
    }

    grid.sync();   // hist/tw zero complete everywhere

    flush_row(lh, hist, s0, d0, t);

    // ---- rows 1..3 ----
    #define DO_ROW(Q, PC, SS, DD)                                              \
    {                                                                          \
        __syncthreads();                                                       \
        zero_lds(lh, t);                                                       \
        __syncthreads();                                                       \
        float wsq = hist_row(residuals, weights, row0 + Q, t, copy, lh, PC);   \
        for (int off = 32; off > 0; off >>= 1) wsq += __shfl_down(wsq, off, 64);\
        if ((t & 63) == 0) swsum[t >> 6] = wsq;                                \
        __syncthreads();                                                       \
        if (t == 0) {                                                          \
            float a = 0.0f;                                                    \
            for (int i = 0; i < 16; ++i) a += swsum[i];                        \
            rowtot[Q] = a;                                                     \
        }                                                                      \
        flush_row(lh, hist, SS, DD, t);                                        \
    }
    DO_ROW(1, pc1, s1, d1)
    DO_ROW(2, pc2, s2, d2)
    DO_ROW(3, pc3, s3, d3)
    #undef DO_ROW

    __syncthreads();
    if (t == 0) {
        gfadd(&tw[s0], rowtot[0]); gfadd(&tw[d0], rowtot[0]);  // both, even if
        gfadd(&tw[s1], rowtot[1]); gfadd(&tw[d1], rowtot[1]);  // s == d
        gfadd(&tw[s2], rowtot[2]); gfadd(&tw[d2], rowtot[2]);
        gfadd(&tw[s3], rowtot[3]); gfadd(&tw[d3], rowtot[3]);
    }

    grid.sync();   // all hist/tw complete

    // ---- scan: blocks 0..127, one node each (threads >=512 idle-sync) ----
    float* fl = (float*)lh;
    if (blk < NUM_NODES) {
        const float denom = tw[blk] + 1e-10f;
        if (t < NUM_BINS) fl[t] = hist[blk * NUM_BINS + t] / denom;
        __syncthreads();
        for (int off = 1; off < NUM_BINS; off <<= 1) {
            float add = (t < NUM_BINS && t >= off) ? fl[t - off] : 0.0f;
            __syncthreads();
            if (t < NUM_BINS) fl[t] += add;
            __syncthreads();
        }
        if (t < NUM_BINS) hist[blk * NUM_BINS + t] = fl[t];
    }

    grid.sync();   // cdf ready

    // ---- lookup, one row at a time (stage src/dst cdf rows in LDS) ----
    #define LOOKUP_ROW(Q, PC, SS, DD)                                          \
    {                                                                          \
        __syncthreads();                                                       \
        if (t < NUM_BINS) {                                                    \
            fl[t]            = hist[SS * NUM_BINS + t];                        \
            fl[NUM_BINS + t] = hist[DD * NUM_BINS + t];                        \
        }                                                                      \
        __syncthreads();                                                       \
        lookup_row(PC, fl, row0 + Q, t, out_src, out_dst);                     \
    }
    LOOKUP_ROW(0, pc0, s0, d0)
    LOOKUP_ROW(1, pc1, s1, d1)
    LOOKUP_ROW(2, pc2, s2, d2)
    LOOKUP_ROW(3, pc3, s3, d3)
    #undef LOOKUP_ROW
}

// ============================ fallback (R8, proven 69us) ====================
__global__ __launch_bounds__(256) void zero_ws_kernel(float* __restrict__ ws, int n)
{
    int i = blockIdx.x * 256 + threadIdx.x;
    if (i < n) ws[i] = 0.0f;
}

__global__ __launch_bounds__(1024) void hist_kernel(
    const float* __restrict__ residuals, const float* __restrict__ weights,
    const int* __restrict__ src, const int* __restrict__ dst,
    float* __restrict__ hist, float* __restrict__ tw,
    u16* __restrict__ codes)
{
    __shared__ u32 lh[NUM_BINS * NCOPY];
    __shared__ float swsum[16];
    const int row  = blockIdx.x;
    const int t    = threadIdx.x;
    const int copy = t & 31;

    uint4* lh4 = (uint4*)lh;
    #pragma unroll
    for (int k = 0; k < NUM_BINS * NCOPY / 4 / 1024; ++k) {
        uint4 z; z.x = z.y = z.z = z.w = 0u;
        lh4[t + k * 1024] = z;
    }
    __syncthreads();

    const f32x4* r4 = (const f32x4*)(residuals + (size_t)row * K_ELEMS);
    const f32x4* w4 = (const f32x4*)(weights   + (size_t)row * K_ELEMS);
    ushort4*     c4 = (ushort4*)(codes + (size_t)row * K_ELEMS);

    float wsum = 0.0f;
    #pragma unroll
    for (int it = 0; it < K_ELEMS / 4 / 1024; ++it) {
        f32x4 r = __builtin_nontemporal_load(r4 + (t + it * 1024));
        f32x4 w = __builtin_nontemporal_load(w4 + (t + it * 1024));
        wsum += w[0] + w[1] + w[2] + w[3];
        ushort4 cv;
        u16* cp = (u16*)&cv;
        #pragma unroll
        for (int c = 0; c < 4; ++c) {
            int b = (int)floorf(r[c] * 512.0f);
            if ((unsigned)b < 512u)
                atomicAdd(&lh[b * NCOPY + copy], (u32)fmaf(w[c], 65536.0f, 0.5f));
            int lb = (int)floorf(r[c] * 512.0f + 0.5f);
            cp[c] = (u16)((((unsigned)lb < 512u) & (w[c] > 0.0f)) ? lb : 0xFFFF);
        }
        c4[t + it * 1024] = cv;
    }

    #pragma unroll
    for (int off = 32; off > 0; off >>= 1) wsum += __shfl_down(wsum, off, 64);
    const int wave = t >> 6, lane = t & 63;
    if (lane == 0) swsum[wave] = wsum;
    __syncthreads();

    const int s = src[row], d = dst[row];
    if (t == 0) {
        float tot = 0.0f;
        #pragma unroll
        for (int i = 0; i < 16; ++i) tot += swsum[i];
        gfadd(&tw[s], tot);
        gfadd(&tw[d], tot);
    }

    {
        const int bin  = t >> 1;
        const int half = t & 1;
        u32 tot = 0;
        #pragma unroll
        for (int cc = 0; cc < 16; ++cc)
            tot += lh[bin * NCOPY + (((bin + cc) & 15) | (half << 4))];
        tot += (u32)__shfl_xor((int)tot, 1);
        float v = (float)tot * (1.0f / 65536.0f);
        if (half == 0) gfadd(&hist[s * NUM_BINS + bin], v);
        else           gfadd(&hist[d * NUM_BINS + bin], v);
    }
}

__global__ __launch_bounds__(512) void scan_kernel(float* __restrict__ hist,
                                                   const float* __restrict__ tw)
{
    __shared__ float s[NUM_BINS];
    const int node = blockIdx.x;
    const int t    = threadIdx.x;

    const float denom = tw[node] + 1e-10f;
    s[t] = hist[node * NUM_BINS + t] / denom;
    __syncthreads();

    for (int off = 1; off < NUM_BINS; off <<= 1) {
        float add = (t >= off) ? s[t - off] : 0.0f;
        __syncthreads();
        s[t] += add;
        __syncthreads();
    }
    hist[node * NUM_BINS + t] = s[t];
}

__global__ __launch_bounds__(256) void lookup_code_kernel(
    const u16* __restrict__ codes,
    const int* __restrict__ src, const int* __restrict__ dst,
    const float* __restrict__ cdf,
    float* __restrict__ out_src, float* __restrict__ out_dst)
{
    __shared__ float scdf[NUM_BINS];
    __shared__ float dcdf[NUM_BINS];
    const int CHUNK = K_ELEMS / 4;
    const int row   = blockIdx.x >> 2;
    const int chunk = blockIdx.x & 3;
    const int t     = threadIdx.x;

    const int s = src[row], d = dst[row];
    for (int i = t; i < NUM_BINS; i += 256) {
        scdf[i] = cdf[s * NUM_BINS + i];
        dcdf[i] = cdf[d * NUM_BINS + i];
    }
    __syncthreads();

    const size_t base = (size_t)row * K_ELEMS + (size_t)chunk * CHUNK;
    const ushort4* c4 = (const ushort4*)(codes + base);
    f32x4*        os4 = (f32x4*)(out_src + base);
    f32x4*        od4 = (f32x4*)(out_dst + base);

    for (int i = t; i < CHUNK / 4; i += 256) {
        ushort4 c = c4[i];
        f32x4 osv, odv;
        osv[0] = (c.x != 0xFFFF) ? scdf[c.x] : 2.0f;
        odv[0] = (c.x != 0xFFFF) ? dcdf[c.x] : 2.0f;
        osv[1] = (c.y != 0xFFFF) ? scdf[c.y] : 2.0f;
        odv[1] = (c.y != 0xFFFF) ? dcdf[c.y] : 2.0f;
        osv[2] = (c.z != 0xFFFF) ? scdf[c.z] : 2.0f;
        odv[2] = (c.z != 0xFFFF) ? dcdf[c.z] : 2.0f;
        osv[3] = (c.w != 0xFFFF) ? scdf[c.w] : 2.0f;
        odv[3] = (c.w != 0xFFFF) ? dcdf[c.w] : 2.0f;
        __builtin_nontemporal_store(osv, os4 + i);
        __builtin_nontemporal_store(odv, od4 + i);
    }
}

// ---------------------------------------------------------------------------
extern "C" void kernel_launch(void* const* d_in, const int* in_sizes, int n_in,
                              void* d_out, int out_size, void* d_ws, size_t ws_size,
                              hipStream_t stream)
{
    const float* residuals = (const float*)d_in[0];
    const float* weights   = (const float*)d_in[1];
    const int*   src       = (const int*)d_in[2];
    const int*   dst       = (const int*)d_in[3];

    float* out_src = (float*)d_out;
    float* out_dst = out_src + (size_t)N_PAIRS * K_ELEMS;

    // ws: hist f32[128][512] (becomes cdf in place), tw f32[128] contiguous;
    // codes (fallback only) at +4 MiB.
    float* hist  = (float*)d_ws;
    float* tw    = hist + NUM_NODES * NUM_BINS;
    u16*   codes = (u16*)((char*)d_ws + (4u << 20));

    void* args[] = {
        (void*)&residuals, (void*)&weights, (void*)&src, (void*)&dst,
        (void*)&hist, (void*)&tw, (void*)&out_src, (void*)&out_dst
    };
    hipError_t e = hipLaunchCooperativeKernel((const void*)fused_kernel,
                                              dim3(NBLK), dim3(NTHR), args,
                                              0, stream);
    if (e != hipSuccess) {
        (void)hipGetLastError();   // clear sticky error, use proven R8 path
        const int ws_elems = NUM_NODES * NUM_BINS + NUM_NODES;
        zero_ws_kernel<<<(ws_elems + 255) / 256, 256, 0, stream>>>((float*)d_ws, ws_elems);
        hist_kernel<<<N_PAIRS, 1024, 0, stream>>>(residuals, weights, src, dst,
                                                  hist, tw, codes);
        scan_kernel<<<NUM_NODES, NUM_BINS, 0, stream>>>(hist, tw);
        lookup_code_kernel<<<N_PAIRS * 4, 256, 0, stream>>>(codes, src, dst, hist,
                                                            out_src, out_dst);
    }
}

// Round 12
// 69.200 us; speedup vs baseline: 2.2138x; 2.2138x over previous
//
#include <hip/hip_runtime.h>

#define NUM_BINS  512
#define NUM_NODES 128
#define K_ELEMS   16384
#define N_PAIRS   1024
#define NCOPY     32

typedef float f32x4 __attribute__((ext_vector_type(4)));
typedef float f32x2 __attribute__((ext_vector_type(2)));
typedef unsigned int   u32;
typedef unsigned short u16;

__device__ __forceinline__ void gfadd(float* p, float v) { unsafeAtomicAdd(p, v); }

// ---------------------------------------------------------------------------
// Pass 0: zero node hist + tw (65,664 floats, ~1us).
// ---------------------------------------------------------------------------
__global__ __launch_bounds__(256) void zero_ws_kernel(float* __restrict__ ws, int n)
{
    int i = blockIdx.x * 256 + threadIdx.x;
    if (i < n) ws[i] = 0.0f;
}

// ---------------------------------------------------------------------------
// Pass 1: per-row histogram (R8-proven). Fixed-point u32 LDS atomics
// (ds_add_u32 = fast bank-parallel path; ds_add_f32 is CU-serialized
// ~3.3 cy/lane, measured R1-R4). 32 copies, copy = tid&31 -> bank = copy:
// 2 lanes/bank (free). 1024 thr, 64 KB LDS -> 2 blocks/CU -> 32 waves/CU.
// Flush: coalesced global f32 atomics. Emits u16 lookup-codes so pass 3
// never re-reads the 128 MiB inputs. Non-temporal input loads (read-once).
// ---------------------------------------------------------------------------
__global__ __launch_bounds__(1024) void hist_kernel(
    const float* __restrict__ residuals, const float* __restrict__ weights,
    const int* __restrict__ src, const int* __restrict__ dst,
    float* __restrict__ hist, float* __restrict__ tw,
    u16* __restrict__ codes)
{
    __shared__ u32 lh[NUM_BINS * NCOPY];   // 65536 B
    __shared__ float swsum[16];
    const int row  = blockIdx.x;
    const int t    = threadIdx.x;
    const int copy = t & 31;

    uint4* lh4 = (uint4*)lh;
    #pragma unroll
    for (int k = 0; k < NUM_BINS * NCOPY / 4 / 1024; ++k) {
        uint4 z; z.x = z.y = z.z = z.w = 0u;
        lh4[t + k * 1024] = z;
    }
    __syncthreads();

    const f32x4* r4 = (const f32x4*)(residuals + (size_t)row * K_ELEMS);
    const f32x4* w4 = (const f32x4*)(weights   + (size_t)row * K_ELEMS);
    ushort4*     c4 = (ushort4*)(codes + (size_t)row * K_ELEMS);

    float wsum = 0.0f;
    #pragma unroll
    for (int it = 0; it < K_ELEMS / 4 / 1024; ++it) {
        f32x4 r = __builtin_nontemporal_load(r4 + (t + it * 1024));
        f32x4 w = __builtin_nontemporal_load(w4 + (t + it * 1024));
        wsum += w[0] + w[1] + w[2] + w[3];     // tw is UNMASKED sum
        ushort4 cv;
        u16* cp = (u16*)&cv;
        #pragma unroll
        for (int c = 0; c < 4; ++c) {
            int b = (int)floorf(r[c] * 512.0f);
            if ((unsigned)b < 512u)
                atomicAdd(&lh[b * NCOPY + copy], (u32)fmaf(w[c], 65536.0f, 0.5f));
            int lb = (int)floorf(r[c] * 512.0f + 0.5f);
            cp[c] = (u16)((((unsigned)lb < 512u) & (w[c] > 0.0f)) ? lb : 0xFFFF);
        }
        c4[t + it * 1024] = cv;
    }

    #pragma unroll
    for (int off = 32; off > 0; off >>= 1) wsum += __shfl_down(wsum, off, 64);
    const int wave = t >> 6, lane = t & 63;
    if (lane == 0) swsum[wave] = wsum;
    __syncthreads();

    const int s = src[row], d = dst[row];
    if (t == 0) {
        float tot = 0.0f;
        #pragma unroll
        for (int i = 0; i < 16; ++i) tot += swsum[i];
        gfadd(&tw[s], tot);
        gfadd(&tw[d], tot);   // both, even if s == d (matches ref)
    }

    // flush: thread pair (2b,2b+1) owns bin b; rotated copies, 2 lanes/bank.
    {
        const int bin  = t >> 1;
        const int half = t & 1;
        u32 tot = 0;
        #pragma unroll
        for (int cc = 0; cc < 16; ++cc)
            tot += lh[bin * NCOPY + (((bin + cc) & 15) | (half << 4))];
        tot += (u32)__shfl_xor((int)tot, 1);
        float v = (float)tot * (1.0f / 65536.0f);
        if (half == 0) gfadd(&hist[s * NUM_BINS + bin], v);
        else           gfadd(&hist[d * NUM_BINS + bin], v);
    }
}

// ---------------------------------------------------------------------------
// Pass 2: pmf = hist / (tw + 1e-10); cdf = inclusive scan. In-place on hist.
// ---------------------------------------------------------------------------
__global__ __launch_bounds__(512) void scan_kernel(float* __restrict__ hist,
                                                   const float* __restrict__ tw)
{
    __shared__ float s[NUM_BINS];
    const int node = blockIdx.x;
    const int t    = threadIdx.x;

    const float denom = tw[node] + 1e-10f;
    s[t] = hist[node * NUM_BINS + t] / denom;
    __syncthreads();

    for (int off = 1; off < NUM_BINS; off <<= 1) {
        float add = (t >= off) ? s[t - off] : 0.0f;
        __syncthreads();
        s[t] += add;
        __syncthreads();
    }
    hist[node * NUM_BINS + t] = s[t];
}

// ---------------------------------------------------------------------------
// Pass 3: lookup from u16 codes. NEW: src/dst cdf rows staged INTERLEAVED as
// float2 -> ONE ds_read_b64 per element instead of two ds_read_b32 from
// tables 2 KB apart (halves scattered-LDS instruction count). Non-temporal
// output stores (write-once stream; keep L2/L3 for codes).
// ---------------------------------------------------------------------------
__global__ __launch_bounds__(256) void lookup_code_kernel(
    const u16* __restrict__ codes,
    const int* __restrict__ src, const int* __restrict__ dst,
    const float* __restrict__ cdf,
    float* __restrict__ out_src, float* __restrict__ out_dst)
{
    __shared__ f32x2 sd[NUM_BINS];          // {src_cdf, dst_cdf} per bin
    const int CHUNK = K_ELEMS / 4;          // 4096 elements per block
    const int row   = blockIdx.x >> 2;
    const int chunk = blockIdx.x & 3;
    const int t     = threadIdx.x;

    const int s = src[row], d = dst[row];
    for (int i = t; i < NUM_BINS; i += 256) {
        f32x2 v;
        v[0] = cdf[s * NUM_BINS + i];
        v[1] = cdf[d * NUM_BINS + i];
        sd[i] = v;
    }
    __syncthreads();

    const size_t base = (size_t)row * K_ELEMS + (size_t)chunk * CHUNK;
    const ushort4* c4 = (const ushort4*)(codes + base);
    f32x4*        os4 = (f32x4*)(out_src + base);
    f32x4*        od4 = (f32x4*)(out_dst + base);

    for (int i = t; i < CHUNK / 4; i += 256) {   // 4 iters
        ushort4 c = c4[i];
        f32x4 osv, odv;
        {   f32x2 v = (c.x != 0xFFFF) ? sd[c.x] : (f32x2){2.0f, 2.0f};
            osv[0] = v[0]; odv[0] = v[1]; }
        {   f32x2 v = (c.y != 0xFFFF) ? sd[c.y] : (f32x2){2.0f, 2.0f};
            osv[1] = v[0]; odv[1] = v[1]; }
        {   f32x2 v = (c.z != 0xFFFF) ? sd[c.z] : (f32x2){2.0f, 2.0f};
            osv[2] = v[0]; odv[2] = v[1]; }
        {   f32x2 v = (c.w != 0xFFFF) ? sd[c.w] : (f32x2){2.0f, 2.0f};
            osv[3] = v[0]; odv[3] = v[1]; }
        __builtin_nontemporal_store(osv, os4 + i);
        __builtin_nontemporal_store(odv, od4 + i);
    }
}

// ---------------------------------------------------------------------------
extern "C" void kernel_launch(void* const* d_in, const int* in_sizes, int n_in,
                              void* d_out, int out_size, void* d_ws, size_t ws_size,
                              hipStream_t stream)
{
    const float* residuals = (const float*)d_in[0];
    const float* weights   = (const float*)d_in[1];
    const int*   src       = (const int*)d_in[2];
    const int*   dst       = (const int*)d_in[3];

    float* out_src = (float*)d_out;
    float* out_dst = out_src + (size_t)N_PAIRS * K_ELEMS;

    // ws: hist f32[128][512] (becomes cdf in place), tw f32[128] contiguous;
    // codes at +4 MiB.
    float* hist  = (float*)d_ws;
    float* tw    = hist + NUM_NODES * NUM_BINS;
    u16*   codes = (u16*)((char*)d_ws + (4u << 20));

    const int ws_elems = NUM_NODES * NUM_BINS + NUM_NODES;
    zero_ws_kernel<<<(ws_elems + 255) / 256, 256, 0, stream>>>((float*)d_ws, ws_elems);

    hist_kernel<<<N_PAIRS, 1024, 0, stream>>>(residuals, weights, src, dst,
                                              hist, tw, codes);

    scan_kernel<<<NUM_NODES, NUM_BINS, 0, stream>>>(hist, tw);

    lookup_code_kernel<<<N_PAIRS * 4, 256, 0, stream>>>(codes, src, dst, hist,
                                                        out_src, out_dst);
}

// Round 13
// 68.034 us; speedup vs baseline: 2.2518x; 1.0171x over previous
//
#include <hip/hip_runtime.h>

#define NUM_BINS  512
#define NUM_NODES 128
#define K_ELEMS   16384
#define N_PAIRS   1024
#define NCOPY     32

typedef float f32x4 __attribute__((ext_vector_type(4)));
typedef float f32x2 __attribute__((ext_vector_type(2)));
typedef unsigned int   u32;
typedef unsigned short u16;

__device__ __forceinline__ void gfadd(float* p, float v) { unsafeAtomicAdd(p, v); }

// ---------------------------------------------------------------------------
// Pass 0: zero node hist + tw (65,664 floats, ~1us).
// ---------------------------------------------------------------------------
__global__ __launch_bounds__(256) void zero_ws_kernel(float* __restrict__ ws, int n)
{
    int i = blockIdx.x * 256 + threadIdx.x;
    if (i < n) ws[i] = 0.0f;
}

// ---------------------------------------------------------------------------
// Pass 1: per-row histogram (R8-proven). Fixed-point u32 LDS atomics
// (ds_add_u32 = fast bank-parallel path; ds_add_f32 is CU-serialized
// ~3.3 cy/lane, measured R1-R4). 32 copies, copy = tid&31 -> bank = copy:
// 2 lanes/bank (free). 1024 thr, 64 KB LDS -> 2 blocks/CU -> 32 waves/CU.
// Flush: coalesced global f32 atomics. Emits u16 lookup-codes so pass 3
// never re-reads the 128 MiB inputs. Non-temporal input loads (read-once).
// ---------------------------------------------------------------------------
__global__ __launch_bounds__(1024) void hist_kernel(
    const float* __restrict__ residuals, const float* __restrict__ weights,
    const int* __restrict__ src, const int* __restrict__ dst,
    float* __restrict__ hist, float* __restrict__ tw,
    u16* __restrict__ codes)
{
    __shared__ u32 lh[NUM_BINS * NCOPY];   // 65536 B
    __shared__ float swsum[16];
    const int row  = blockIdx.x;
    const int t    = threadIdx.x;
    const int copy = t & 31;

    uint4* lh4 = (uint4*)lh;
    #pragma unroll
    for (int k = 0; k < NUM_BINS * NCOPY / 4 / 1024; ++k) {
        uint4 z; z.x = z.y = z.z = z.w = 0u;
        lh4[t + k * 1024] = z;
    }
    __syncthreads();

    const f32x4* r4 = (const f32x4*)(residuals + (size_t)row * K_ELEMS);
    const f32x4* w4 = (const f32x4*)(weights   + (size_t)row * K_ELEMS);
    ushort4*     c4 = (ushort4*)(codes + (size_t)row * K_ELEMS);

    float wsum = 0.0f;
    #pragma unroll
    for (int it = 0; it < K_ELEMS / 4 / 1024; ++it) {
        f32x4 r = __builtin_nontemporal_load(r4 + (t + it * 1024));
        f32x4 w = __builtin_nontemporal_load(w4 + (t + it * 1024));
        wsum += w[0] + w[1] + w[2] + w[3];     // tw is UNMASKED sum
        ushort4 cv;
        u16* cp = (u16*)&cv;
        #pragma unroll
        for (int c = 0; c < 4; ++c) {
            int b = (int)floorf(r[c] * 512.0f);
            if ((unsigned)b < 512u)
                atomicAdd(&lh[b * NCOPY + copy], (u32)fmaf(w[c], 65536.0f, 0.5f));
            int lb = (int)floorf(r[c] * 512.0f + 0.5f);
            cp[c] = (u16)((((unsigned)lb < 512u) & (w[c] > 0.0f)) ? lb : 0xFFFF);
        }
        c4[t + it * 1024] = cv;
    }

    #pragma unroll
    for (int off = 32; off > 0; off >>= 1) wsum += __shfl_down(wsum, off, 64);
    const int wave = t >> 6, lane = t & 63;
    if (lane == 0) swsum[wave] = wsum;
    __syncthreads();

    const int s = src[row], d = dst[row];
    if (t == 0) {
        float tot = 0.0f;
        #pragma unroll
        for (int i = 0; i < 16; ++i) tot += swsum[i];
        gfadd(&tw[s], tot);
        gfadd(&tw[d], tot);   // both, even if s == d (matches ref)
    }

    // flush: thread pair (2b,2b+1) owns bin b; rotated copies, 2 lanes/bank.
    {
        const int bin  = t >> 1;
        const int half = t & 1;
        u32 tot = 0;
        #pragma unroll
        for (int cc = 0; cc < 16; ++cc)
            tot += lh[bin * NCOPY + (((bin + cc) & 15) | (half << 4))];
        tot += (u32)__shfl_xor((int)tot, 1);
        float v = (float)tot * (1.0f / 65536.0f);
        if (half == 0) gfadd(&hist[s * NUM_BINS + bin], v);
        else           gfadd(&hist[d * NUM_BINS + bin], v);
    }
}

// ---------------------------------------------------------------------------
// Pass 2 (fused scan+lookup): one block (512 thr) per row.
//  - stage {hist[s][t]/denom_s, hist[d][t]/denom_d} as f32x2
//  - Hillis-Steele inclusive scan over 512 bins (512 threads, SAME add order
//    as the old scan_kernel -> bitwise-identical cdf)
//  - lookup the row's 16384 codes, nt-store both outputs.
// Saves one dispatch + its gap + the cdf global round-trip.
// ---------------------------------------------------------------------------
__global__ __launch_bounds__(512) void lookup_scan_kernel(
    const u16* __restrict__ codes,
    const int* __restrict__ src, const int* __restrict__ dst,
    const float* __restrict__ hist, const float* __restrict__ tw,
    float* __restrict__ out_src, float* __restrict__ out_dst)
{
    __shared__ f32x2 sd[NUM_BINS];          // {src_cdf, dst_cdf} per bin
    const int row = blockIdx.x;
    const int t   = threadIdx.x;            // 0..511

    const int s = src[row], d = dst[row];
    {
        f32x2 v;
        v[0] = hist[s * NUM_BINS + t] / (tw[s] + 1e-10f);
        v[1] = hist[d * NUM_BINS + t] / (tw[d] + 1e-10f);
        sd[t] = v;
    }
    __syncthreads();

    for (int off = 1; off < NUM_BINS; off <<= 1) {
        f32x2 add = (t >= off) ? sd[t - off] : (f32x2){0.0f, 0.0f};
        __syncthreads();
        sd[t] += add;
        __syncthreads();
    }

    const size_t base = (size_t)row * K_ELEMS;
    const ushort4* c4 = (const ushort4*)(codes + base);
    f32x4*        os4 = (f32x4*)(out_src + base);
    f32x4*        od4 = (f32x4*)(out_dst + base);

    #pragma unroll
    for (int it = 0; it < K_ELEMS / 4 / 512; ++it) {   // 8 iters
        ushort4 c = c4[t + it * 512];
        f32x4 osv, odv;
        {   f32x2 v = (c.x != 0xFFFF) ? sd[c.x] : (f32x2){2.0f, 2.0f};
            osv[0] = v[0]; odv[0] = v[1]; }
        {   f32x2 v = (c.y != 0xFFFF) ? sd[c.y] : (f32x2){2.0f, 2.0f};
            osv[1] = v[0]; odv[1] = v[1]; }
        {   f32x2 v = (c.z != 0xFFFF) ? sd[c.z] : (f32x2){2.0f, 2.0f};
            osv[2] = v[0]; odv[2] = v[1]; }
        {   f32x2 v = (c.w != 0xFFFF) ? sd[c.w] : (f32x2){2.0f, 2.0f};
            osv[3] = v[0]; odv[3] = v[1]; }
        __builtin_nontemporal_store(osv, os4 + (t + it * 512));
        __builtin_nontemporal_store(odv, od4 + (t + it * 512));
    }
}

// ---------------------------------------------------------------------------
extern "C" void kernel_launch(void* const* d_in, const int* in_sizes, int n_in,
                              void* d_out, int out_size, void* d_ws, size_t ws_size,
                              hipStream_t stream)
{
    const float* residuals = (const float*)d_in[0];
    const float* weights   = (const float*)d_in[1];
    const int*   src       = (const int*)d_in[2];
    const int*   dst       = (const int*)d_in[3];

    float* out_src = (float*)d_out;
    float* out_dst = out_src + (size_t)N_PAIRS * K_ELEMS;

    // ws: hist f32[128][512], tw f32[128] contiguous; codes at +4 MiB.
    float* hist  = (float*)d_ws;
    float* tw    = hist + NUM_NODES * NUM_BINS;
    u16*   codes = (u16*)((char*)d_ws + (4u << 20));

    const int ws_elems = NUM_NODES * NUM_BINS + NUM_NODES;
    zero_ws_kernel<<<(ws_elems + 255) / 256, 256, 0, stream>>>((float*)d_ws, ws_elems);

    hist_kernel<<<N_PAIRS, 1024, 0, stream>>>(residuals, weights, src, dst,
                                              hist, tw, codes);

    lookup_scan_kernel<<<N_PAIRS, 512, 0, stream>>>(codes, src, dst, hist, tw,
                                                    out_src, out_dst);
}

// Round 14
// 66.680 us; speedup vs baseline: 2.2975x; 1.0203x over previous
//
#include <hip/hip_runtime.h>

#define NUM_BINS  512
#define NUM_NODES 128
#define K_ELEMS   16384
#define N_PAIRS   1024
#define NCOPY     32

typedef float f32x4 __attribute__((ext_vector_type(4)));
typedef float f32x2 __attribute__((ext_vector_type(2)));
typedef unsigned int   u32;
typedef unsigned short u16;

__device__ __forceinline__ void gfadd(float* p, float v) { unsafeAtomicAdd(p, v); }

// ---------------------------------------------------------------------------
// Pass 0: zero node hist + tw (65,664 floats, ~1us).
// ---------------------------------------------------------------------------
__global__ __launch_bounds__(256) void zero_ws_kernel(float* __restrict__ ws, int n)
{
    int i = blockIdx.x * 256 + threadIdx.x;
    if (i < n) ws[i] = 0.0f;
}

// ---------------------------------------------------------------------------
// Pass 1: per-row histogram. Fixed-point u32 LDS atomics (ds_add_u32 = fast
// bank-parallel path; ds_add_f32 is CU-serialized ~3.3 cy/lane, R1-R4).
// 32 copies, copy = tid&31 -> bank = copy: 2 lanes/bank (free).
// 1024 thr, 64 KB LDS -> 2 blocks/CU -> 32 waves/CU.
// NEW vs R13: instead of 32 MiB u16 codes, write a 2 MiB packed validity
// bitmask (bit = bin-in-range & w>0); lookup re-derives the bin from the
// residual. Residuals loaded WITHOUT nt (stay L3-resident for the lookup
// re-read); weights nt (truly read-once).
// ---------------------------------------------------------------------------
__global__ __launch_bounds__(1024) void hist_kernel(
    const float* __restrict__ residuals, const float* __restrict__ weights,
    const int* __restrict__ src, const int* __restrict__ dst,
    float* __restrict__ hist, float* __restrict__ tw,
    u16* __restrict__ mask)
{
    __shared__ u32 lh[NUM_BINS * NCOPY];   // 65536 B
    __shared__ float swsum[16];
    const int row  = blockIdx.x;
    const int t    = threadIdx.x;
    const int copy = t & 31;

    uint4* lh4 = (uint4*)lh;
    #pragma unroll
    for (int k = 0; k < NUM_BINS * NCOPY / 4 / 1024; ++k) {
        uint4 z; z.x = z.y = z.z = z.w = 0u;
        lh4[t + k * 1024] = z;
    }
    __syncthreads();

    const f32x4* r4 = (const f32x4*)(residuals + (size_t)row * K_ELEMS);
    const f32x4* w4 = (const f32x4*)(weights   + (size_t)row * K_ELEMS);

    float wsum = 0.0f;
    u32 vbits = 0;
    #pragma unroll
    for (int it = 0; it < K_ELEMS / 4 / 1024; ++it) {   // 4 iters
        f32x4 r = r4[t + it * 1024];                            // cacheable
        f32x4 w = __builtin_nontemporal_load(w4 + (t + it * 1024));  // nt
        wsum += w[0] + w[1] + w[2] + w[3];     // tw is UNMASKED sum
        #pragma unroll
        for (int c = 0; c < 4; ++c) {
            int b = (int)floorf(r[c] * 512.0f);
            if ((unsigned)b < 512u)
                atomicAdd(&lh[b * NCOPY + copy], (u32)fmaf(w[c], 65536.0f, 0.5f));
            int lb = (int)floorf(r[c] * 512.0f + 0.5f);
            if (((unsigned)lb < 512u) & (w[c] > 0.0f))
                vbits |= 1u << (it * 4 + c);
        }
    }
    mask[(size_t)row * 1024 + t] = (u16)vbits;

    #pragma unroll
    for (int off = 32; off > 0; off >>= 1) wsum += __shfl_down(wsum, off, 64);
    const int wave = t >> 6, lane = t & 63;
    if (lane == 0) swsum[wave] = wsum;
    __syncthreads();

    const int s = src[row], d = dst[row];
    if (t == 0) {
        float tot = 0.0f;
        #pragma unroll
        for (int i = 0; i < 16; ++i) tot += swsum[i];
        gfadd(&tw[s], tot);
        gfadd(&tw[d], tot);   // both, even if s == d (matches ref)
    }

    // flush: thread pair (2b,2b+1) owns bin b; rotated copies, 2 lanes/bank.
    {
        const int bin  = t >> 1;
        const int half = t & 1;
        u32 tot = 0;
        #pragma unroll
        for (int cc = 0; cc < 16; ++cc)
            tot += lh[bin * NCOPY + (((bin + cc) & 15) | (half << 4))];
        tot += (u32)__shfl_xor((int)tot, 1);
        float v = (float)tot * (1.0f / 65536.0f);
        if (half == 0) gfadd(&hist[s * NUM_BINS + bin], v);
        else           gfadd(&hist[d * NUM_BINS + bin], v);
    }
}

// ---------------------------------------------------------------------------
// Pass 2 (fused scan+lookup): one block (512 thr) per row.
//  - stage {hist[s][t]/denom_s, hist[d][t]/denom_d} as f32x2, Hillis-Steele
//    scan (same add order as before -> bitwise-identical cdf)
//  - re-read residuals (L3-hot), recompute bin, validity from 2 MiB mask,
//    nt-store both outputs.
// Mask indexing: element e = 4q+c, q = t + it*512. Hist thread owning q is
// (q & 1023) in {t, t+512}; its bit is ((q>>10)*4 + c) = ((it>>1)*4 + c).
// ---------------------------------------------------------------------------
__global__ __launch_bounds__(512) void lookup_scan_kernel(
    const float* __restrict__ residuals, const u16* __restrict__ mask,
    const int* __restrict__ src, const int* __restrict__ dst,
    const float* __restrict__ hist, const float* __restrict__ tw,
    float* __restrict__ out_src, float* __restrict__ out_dst)
{
    __shared__ f32x2 sd[NUM_BINS];          // {src_cdf, dst_cdf} per bin
    const int row = blockIdx.x;
    const int t   = threadIdx.x;            // 0..511

    const int s = src[row], d = dst[row];
    {
        f32x2 v;
        v[0] = hist[s * NUM_BINS + t] / (tw[s] + 1e-10f);
        v[1] = hist[d * NUM_BINS + t] / (tw[d] + 1e-10f);
        sd[t] = v;
    }
    __syncthreads();

    for (int off = 1; off < NUM_BINS; off <<= 1) {
        f32x2 add = (t >= off) ? sd[t - off] : (f32x2){0.0f, 0.0f};
        __syncthreads();
        sd[t] += add;
        __syncthreads();
    }

    const size_t base = (size_t)row * K_ELEMS;
    const f32x4* r4   = (const f32x4*)(residuals + base);
    f32x4*       os4  = (f32x4*)(out_src + base);
    f32x4*       od4  = (f32x4*)(out_dst + base);

    const u32 m0 = mask[(size_t)row * 1024 + t];
    const u32 m1 = mask[(size_t)row * 1024 + t + 512];

    #pragma unroll
    for (int it = 0; it < K_ELEMS / 4 / 512; ++it) {   // 8 iters
        const int q = t + it * 512;
        const u32 mw = (it & 1) ? m1 : m0;
        const int kb = (it >> 1) * 4;
        f32x4 r = r4[q];
        f32x4 osv, odv;
        #pragma unroll
        for (int c = 0; c < 4; ++c) {
            int lb = (int)floorf(r[c] * 512.0f + 0.5f);
            int bc = min(max(lb, 0), NUM_BINS - 1);     // safe LDS addr
            bool v = (mw >> (kb + c)) & 1u;
            f32x2 vv = v ? sd[bc] : (f32x2){2.0f, 2.0f};
            osv[c] = vv[0]; odv[c] = vv[1];
        }
        __builtin_nontemporal_store(osv, os4 + q);
        __builtin_nontemporal_store(odv, od4 + q);
    }
}

// ---------------------------------------------------------------------------
extern "C" void kernel_launch(void* const* d_in, const int* in_sizes, int n_in,
                              void* d_out, int out_size, void* d_ws, size_t ws_size,
                              hipStream_t stream)
{
    const float* residuals = (const float*)d_in[0];
    const float* weights   = (const float*)d_in[1];
    const int*   src       = (const int*)d_in[2];
    const int*   dst       = (const int*)d_in[3];

    float* out_src = (float*)d_out;
    float* out_dst = out_src + (size_t)N_PAIRS * K_ELEMS;

    // ws: hist f32[128][512], tw f32[128] contiguous; mask u16[1024*1024]
    // (2 MiB) at +4 MiB.
    float* hist = (float*)d_ws;
    float* tw   = hist + NUM_NODES * NUM_BINS;
    u16*   mask = (u16*)((char*)d_ws + (4u << 20));

    const int ws_elems = NUM_NODES * NUM_BINS + NUM_NODES;
    zero_ws_kernel<<<(ws_elems + 255) / 256, 256, 0, stream>>>((float*)d_ws, ws_elems);

    hist_kernel<<<N_PAIRS, 1024, 0, stream>>>(residuals, weights, src, dst,
                                              hist, tw, mask);

    lookup_scan_kernel<<<N_PAIRS, 512, 0, stream>>>(residuals, mask, src, dst,
                                                    hist, tw, out_src, out_dst);
}

// Round 15
// 64.543 us; speedup vs baseline: 2.3736x; 1.0331x over previous
//
#include <hip/hip_runtime.h>

#define NUM_BINS  512
#define NUM_NODES 128
#define K_ELEMS   16384
#define N_PAIRS   1024
#define NCOPY     16

typedef float f32x4 __attribute__((ext_vector_type(4)));
typedef float f32x2 __attribute__((ext_vector_type(2)));
typedef unsigned int   u32;
typedef unsigned short u16;

__device__ __forceinline__ void gfadd(float* p, float v) { unsafeAtomicAdd(p, v); }

// ---------------------------------------------------------------------------
// Pass 0: zero node hist + tw (65,664 floats, ~1us).
// ---------------------------------------------------------------------------
__global__ __launch_bounds__(256) void zero_ws_kernel(float* __restrict__ ws, int n)
{
    int i = blockIdx.x * 256 + threadIdx.x;
    if (i < n) ws[i] = 0.0f;
}

// ---------------------------------------------------------------------------
// Pass 1: per-row histogram. Fixed-point u32 LDS atomics (ds_add_u32 = fast
// bank-parallel path; ds_add_f32 is CU-serialized, measured R1-R4).
// NEW vs R14: 512 thr + NCOPY=16 (32 KB LDS) -> 4 blocks/CU x 8 waves =
// 32 waves/CU with VGPR budget 128 (was 64) -> room for depth-2 prefetch.
// Worst-case LDS atomic aliasing 4-way (atomic op only) - acceptable.
// Writes 2 MiB u32 validity bitmask; weights nt (read-once), residuals
// cacheable (lookup re-reads them).
// ---------------------------------------------------------------------------
__global__ __launch_bounds__(512) void hist_kernel(
    const float* __restrict__ residuals, const float* __restrict__ weights,
    const int* __restrict__ src, const int* __restrict__ dst,
    float* __restrict__ hist, float* __restrict__ tw,
    u32* __restrict__ mask)
{
    __shared__ u32 lh[NUM_BINS * NCOPY];   // 32768 B
    __shared__ float swsum[8];
    const int row  = blockIdx.x;
    const int t    = threadIdx.x;          // 0..511
    const int copy = t & 15;

    uint4* lh4 = (uint4*)lh;
    #pragma unroll
    for (int k = 0; k < NUM_BINS * NCOPY / 4 / 512; ++k) {   // 4
        uint4 z; z.x = z.y = z.z = z.w = 0u;
        lh4[t + k * 512] = z;
    }
    __syncthreads();

    const f32x4* r4 = (const f32x4*)(residuals + (size_t)row * K_ELEMS);
    const f32x4* w4 = (const f32x4*)(weights   + (size_t)row * K_ELEMS);

    float wsum = 0.0f;
    u32 vbits = 0;

    // depth-2 software prefetch over 8 iterations
    f32x4 rA = r4[t];
    f32x4 wA = __builtin_nontemporal_load(w4 + t);
    #pragma unroll
    for (int it = 0; it < K_ELEMS / 4 / 512; ++it) {   // 8 iters
        f32x4 rB, wB;
        if (it < K_ELEMS / 4 / 512 - 1) {
            rB = r4[t + (it + 1) * 512];
            wB = __builtin_nontemporal_load(w4 + (t + (it + 1) * 512));
        }
        wsum += wA[0] + wA[1] + wA[2] + wA[3];     // tw is UNMASKED sum
        #pragma unroll
        for (int c = 0; c < 4; ++c) {
            int b = (int)floorf(rA[c] * 512.0f);
            if ((unsigned)b < 512u)
                atomicAdd(&lh[b * NCOPY + copy], (u32)fmaf(wA[c], 65536.0f, 0.5f));
            int lb = (int)floorf(rA[c] * 512.0f + 0.5f);
            if (((unsigned)lb < 512u) & (wA[c] > 0.0f))
                vbits |= 1u << (it * 4 + c);
        }
        rA = rB; wA = wB;
    }
    mask[(size_t)row * 512 + t] = vbits;

    #pragma unroll
    for (int off = 32; off > 0; off >>= 1) wsum += __shfl_down(wsum, off, 64);
    const int wave = t >> 6, lane = t & 63;
    if (lane == 0) swsum[wave] = wsum;
    __syncthreads();

    const int s = src[row], d = dst[row];
    if (t == 0) {
        float tot = 0.0f;
        #pragma unroll
        for (int i = 0; i < 8; ++i) tot += swsum[i];
        gfadd(&tw[s], tot);
        gfadd(&tw[d], tot);   // both, even if s == d (matches ref)
    }

    // flush: thread t owns bin t; rotated copy index; coalesced f32 atomics.
    {
        u32 tot = 0;
        #pragma unroll
        for (int cc = 0; cc < NCOPY; ++cc)
            tot += lh[t * NCOPY + ((t + cc) & 15)];
        float v = (float)tot * (1.0f / 65536.0f);
        gfadd(&hist[s * NUM_BINS + t], v);
        gfadd(&hist[d * NUM_BINS + t], v);
    }
}

// ---------------------------------------------------------------------------
// Pass 2 (fused scan+lookup): one block (512 thr) per row.
//  - issue ALL residual re-read loads FIRST (T14 issue-early): their latency
//    hides under the scan's ~20 barriers
//  - stage {hist[s][t]/denom_s, hist[d][t]/denom_d} as f32x2, Hillis-Steele
//    scan (same add order as before -> bitwise-identical cdf)
//  - recompute bin from residual, validity from u32 mask, nt-store outputs.
// Mask bit for elem 4*(t+it*512)+c is it*4+c of word mask[row*512+t].
// ---------------------------------------------------------------------------
__global__ __launch_bounds__(512) void lookup_scan_kernel(
    const float* __restrict__ residuals, const u32* __restrict__ mask,
    const int* __restrict__ src, const int* __restrict__ dst,
    const float* __restrict__ hist, const float* __restrict__ tw,
    float* __restrict__ out_src, float* __restrict__ out_dst)
{
    __shared__ f32x2 sd[NUM_BINS];          // {src_cdf, dst_cdf} per bin
    const int row = blockIdx.x;
    const int t   = threadIdx.x;            // 0..511

    const size_t base = (size_t)row * K_ELEMS;
    const f32x4* r4   = (const f32x4*)(residuals + base);

    // issue-early: all 8 residual vec-loads + the mask word
    f32x4 rr0 = r4[t],           rr1 = r4[t + 512];
    f32x4 rr2 = r4[t + 1024],    rr3 = r4[t + 1536];
    f32x4 rr4 = r4[t + 2048],    rr5 = r4[t + 2560];
    f32x4 rr6 = r4[t + 3072],    rr7 = r4[t + 3584];
    const u32 mw = mask[(size_t)row * 512 + t];

    const int s = src[row], d = dst[row];
    {
        f32x2 v;
        v[0] = hist[s * NUM_BINS + t] / (tw[s] + 1e-10f);
        v[1] = hist[d * NUM_BINS + t] / (tw[d] + 1e-10f);
        sd[t] = v;
    }
    __syncthreads();

    for (int off = 1; off < NUM_BINS; off <<= 1) {
        f32x2 add = (t >= off) ? sd[t - off] : (f32x2){0.0f, 0.0f};
        __syncthreads();
        sd[t] += add;
        __syncthreads();
    }

    f32x4* os4 = (f32x4*)(out_src + base);
    f32x4* od4 = (f32x4*)(out_dst + base);

    #define EMIT(IT, RV)                                                       \
    {                                                                          \
        f32x4 osv, odv;                                                        \
        _Pragma("unroll")                                                      \
        for (int c = 0; c < 4; ++c) {                                          \
            int lb = (int)floorf(RV[c] * 512.0f + 0.5f);                       \
            int bc = min(max(lb, 0), NUM_BINS - 1);                            \
            bool v = (mw >> (IT * 4 + c)) & 1u;                                \
            f32x2 vv = v ? sd[bc] : (f32x2){2.0f, 2.0f};                       \
            osv[c] = vv[0]; odv[c] = vv[1];                                    \
        }                                                                      \
        __builtin_nontemporal_store(osv, os4 + (t + IT * 512));                \
        __builtin_nontemporal_store(odv, od4 + (t + IT * 512));                \
    }
    EMIT(0, rr0) EMIT(1, rr1) EMIT(2, rr2) EMIT(3, rr3)
    EMIT(4, rr4) EMIT(5, rr5) EMIT(6, rr6) EMIT(7, rr7)
    #undef EMIT
}

// ---------------------------------------------------------------------------
extern "C" void kernel_launch(void* const* d_in, const int* in_sizes, int n_in,
                              void* d_out, int out_size, void* d_ws, size_t ws_size,
                              hipStream_t stream)
{
    const float* residuals = (const float*)d_in[0];
    const float* weights   = (const float*)d_in[1];
    const int*   src       = (const int*)d_in[2];
    const int*   dst       = (const int*)d_in[3];

    float* out_src = (float*)d_out;
    float* out_dst = out_src + (size_t)N_PAIRS * K_ELEMS;

    // ws: hist f32[128][512], tw f32[128] contiguous; mask u32[1024*512]
    // (2 MiB) at +4 MiB.
    float* hist = (float*)d_ws;
    float* tw   = hist + NUM_NODES * NUM_BINS;
    u32*   mask = (u32*)((char*)d_ws + (4u << 20));

    const int ws_elems = NUM_NODES * NUM_BINS + NUM_NODES;
    zero_ws_kernel<<<(ws_elems + 255) / 256, 256, 0, stream>>>((float*)d_ws, ws_elems);

    hist_kernel<<<N_PAIRS, 512, 0, stream>>>(residuals, weights, src, dst,
                                             hist, tw, mask);

    lookup_scan_kernel<<<N_PAIRS, 512, 0, stream>>>(residuals, mask, src, dst,
                                                    hist, tw, out_src, out_dst);
}